// Round 9
// baseline (400.124 us; speedup 1.0000x reference)
//
#include <hip/hip_runtime.h>

typedef __bf16 bf16_t;
typedef bf16_t bf16x8 __attribute__((ext_vector_type(8)));
typedef bf16_t bf16x4 __attribute__((ext_vector_type(4)));
typedef float f32x4 __attribute__((ext_vector_type(4)));

#define BATCH 4
#define SEQ 4096
#define EMBED 512
#define MTOT (BATCH * SEQ)
#define BC 32
#define FITERS (SEQ / BC)     // 128 iters, full key range per block

__device__ bf16_t Wbf_g[EMBED * EMBED];  // W pre-converted to bf16

// async global->LDS, 16 B per lane; lds base must be wave-uniform
__device__ __forceinline__ void async_copy16(const bf16_t* g, bf16_t* l) {
    __builtin_amdgcn_global_load_lds(
        (const __attribute__((address_space(1))) unsigned int*)g,
        (__attribute__((address_space(3))) unsigned int*)l, 16, 0, 0);
}

// ---------------------------------------------------------------------------
// Stage 0a: W fp32 -> bf16 once.
// ---------------------------------------------------------------------------
__global__ __launch_bounds__(256) void cvt_w_kernel(const float* __restrict__ W) {
    const int i = (blockIdx.x * 256 + threadIdx.x) * 4;
    float4 v = *(const float4*)&W[i];
    bf16x4 o;
    o[0] = (bf16_t)v.x; o[1] = (bf16_t)v.y; o[2] = (bf16_t)v.z; o[3] = (bf16_t)v.w;
    *(bf16x4*)&Wbf_g[i] = o;
}

// ---------------------------------------------------------------------------
// Stage 0b: abuf = bf16(cos(x + theta)) — A operand precomputed once.
// ---------------------------------------------------------------------------
__global__ __launch_bounds__(256) void cvt_a_kernel(
    const float* __restrict__ x, const float* __restrict__ theta,
    bf16_t* __restrict__ abuf)
{
    const int i = (blockIdx.x * 256 + threadIdx.x) * 8;
    float4 a = *(const float4*)&x[i];
    float4 b = *(const float4*)&x[i + 4];
    const int e0 = i & 63;            // 8-aligned, no wrap within 8 elems
    bf16x8 o;
    o[0] = (bf16_t)__cosf(a.x + theta[e0 + 0]);
    o[1] = (bf16_t)__cosf(a.y + theta[e0 + 1]);
    o[2] = (bf16_t)__cosf(a.z + theta[e0 + 2]);
    o[3] = (bf16_t)__cosf(a.w + theta[e0 + 3]);
    o[4] = (bf16_t)__cosf(b.x + theta[e0 + 4]);
    o[5] = (bf16_t)__cosf(b.y + theta[e0 + 5]);
    o[6] = (bf16_t)__cosf(b.z + theta[e0 + 6]);
    o[7] = (bf16_t)__cosf(b.w + theta[e0 + 7]);
    *(bf16x8*)&abuf[i] = o;
}

// ---------------------------------------------------------------------------
// Stage 1: q = A @ W^T + b (M=16384, N=512, K=512), 128x128xBK64 MFMA GEMM,
// T2 both-sides swizzle, double-buffered staging, LDS-bounce epilogue
// (unchanged from R7). Writes kperm (MFMA-frag-major) + qt (e-major).
// ---------------------------------------------------------------------------
__global__ __launch_bounds__(256, 2) void gemm_q_kernel(
    const bf16_t* __restrict__ abuf, const float* __restrict__ bias,
    bf16_t* __restrict__ kperm, bf16_t* __restrict__ qt)
{
    __shared__ alignas(16) bf16_t smem[4 * 8192];  // 64 KB: [buf][As 16KB|Bs 16KB]

    const int t    = threadIdx.x;
    const int lane = t & 63;
    const int wave = t >> 6;
    const int l15  = lane & 15;
    const int quad = lane >> 4;
    const int m0   = (blockIdx.x >> 2) * 128;     // 128 m-tiles
    const int n0   = (blockIdx.x & 3) * 128;      // 4 n-tiles
    const int wm   = wave >> 1;                   // 0..1
    const int wn   = wave & 1;                    // 0..1

    const int drow = lane >> 3;                   // 0..7 (row within 8-row chunk)
    const int dseg = lane & 7;                    // 0..7 (16B segment)
    const int sseg = dseg ^ drow;                 // pre-swizzled source segment

    f32x4 acc[4][4];
#pragma unroll
    for (int mt = 0; mt < 4; ++mt)
#pragma unroll
        for (int nt = 0; nt < 4; ++nt) acc[mt][nt] = (f32x4){0.f, 0.f, 0.f, 0.f};

    auto stage = [&](int buf, int k0) {
        bf16_t* As = smem + buf * 16384;
        bf16_t* Bs = As + 8192;
#pragma unroll
        for (int j = 0; j < 4; ++j) {
            const int c   = wave * 4 + j;         // chunk 0..15 = rows c*8..c*8+7
            const int row = c * 8 + drow;
            async_copy16(&abuf[(size_t)(m0 + row) * 512 + k0 + sseg * 8], &As[c * 512]);
            async_copy16(&Wbf_g[(size_t)(n0 + row) * 512 + k0 + sseg * 8], &Bs[c * 512]);
        }
    };

    stage(0, 0);
    __syncthreads();            // DMA(0) landed
    int cur = 0;
    for (int kk = 0; kk < 8; ++kk) {
        if (kk + 1 < 8) stage(cur ^ 1, (kk + 1) * 64);   // prefetch next tile
        const bf16_t* As = smem + cur * 16384;
        const bf16_t* Bs = As + 8192;
#pragma unroll
        for (int kh = 0; kh < 2; ++kh) {
            bf16x8 af[4], bfr[4];
#pragma unroll
            for (int i = 0; i < 4; ++i) {
                const int rA = wm * 64 + i * 16 + l15;
                const int rB = wn * 64 + i * 16 + l15;
                const int sg = kh * 4 + quad;
                af[i]  = *(const bf16x8*)&As[rA * 64 + (sg ^ (rA & 7)) * 8];
                bfr[i] = *(const bf16x8*)&Bs[rB * 64 + (sg ^ (rB & 7)) * 8];
            }
#pragma unroll
            for (int mt = 0; mt < 4; ++mt)
#pragma unroll
                for (int nt = 0; nt < 4; ++nt)
                    acc[mt][nt] = __builtin_amdgcn_mfma_f32_16x16x32_bf16(af[mt], bfr[nt], acc[mt][nt], 0, 0, 0);
        }
        __syncthreads();        // drains prefetch DMA (covered by compute); frees cur
        cur ^= 1;
    }

    const int b     = m0 >> 12;          // batch
    const int mloc  = m0 & 4095;         // row base within batch (mult of 128)
    bf16_t* Es = smem;                   // 34 KB bounce, aliases staging bufs

    // ---- pass 1: kperm via LDS bounce ----
#pragma unroll
    for (int nt = 0; nt < 4; ++nt) {
        const int colL = wn * 64 + nt * 16 + l15;
        const float bv = bias[n0 + colL];
        const int kfL = colL >> 5;
        const int inc = ((colL >> 3) & 3) * 128 + (colL & 7);
#pragma unroll
        for (int mt = 0; mt < 4; ++mt) {
            const int rowL0 = wm * 64 + mt * 16 + quad * 4;
            const int c     = (rowL0 >> 5) * 8 + ((rowL0 >> 4) & 1) * 4 + kfL;
            const int base  = c * 512 + inc + (rowL0 & 15) * 8;
#pragma unroll
            for (int r = 0; r < 4; ++r)
                Es[base + r * 8] = (bf16_t)(acc[mt][nt][r] + bv);
        }
    }
    __syncthreads();
    {
        const int tileB = mloc >> 5;
        const int kfB   = n0 >> 5;
#pragma unroll
        for (int p = 0; p < 8; ++p) {
            const int flat = p * 256 + t;          // 0..2047
            const int c2   = flat >> 6;            // chunk 0..31
            const int off  = (flat & 63) * 8;
            const int tile = c2 >> 3;
            const int mh   = (c2 >> 2) & 1;
            const int kfL2 = c2 & 3;
            const size_t dst = (size_t)b * (SEQ * EMBED)
                             + (size_t)(tileB + tile) * 16384
                             + (size_t)(mh * 16 + kfB + kfL2) * 512 + off;
            *(bf16x8*)&kperm[dst] = *(const bf16x8*)&Es[c2 * 512 + off];
        }
    }
    __syncthreads();
    // ---- pass 2: qt via LDS transpose, Es as [colL][136] ----
#pragma unroll
    for (int nt = 0; nt < 4; ++nt) {
        const int colL = wn * 64 + nt * 16 + l15;
        const float bv = bias[n0 + colL];
#pragma unroll
        for (int mt = 0; mt < 4; ++mt) {
            const int rowL0 = wm * 64 + mt * 16 + quad * 4;
#pragma unroll
            for (int r = 0; r < 4; ++r)
                Es[colL * 136 + rowL0 + r] = (bf16_t)(acc[mt][nt][r] + bv);
        }
    }
    __syncthreads();
    {
#pragma unroll
        for (int p = 0; p < 8; ++p) {
            const int flat = p * 256 + t;          // 0..2047
            const int col  = flat >> 4;            // 0..127
            const int sub  = flat & 15;            // 8-row chunk
            *(bf16x8*)&qt[((size_t)(b * 512 + n0 + col) << 12) + mloc + sub * 8]
                = *(const bf16x8*)&Es[col * 136 + sub * 8];
        }
    }
}

// ---------------------------------------------------------------------------
// Stage 2: attention, wave-specialized producer/consumer. Br=32, Bc=32,
// 512 thr / 8 waves, grid 512 = 2 blocks/CU -> 4 waves/SIMD (LDS ~70KB,
// VGPR capped at 128 via launch_bounds(512,4); separated loops keep bQ and
// O in disjoint live ranges).
//   waves 0-3 (QK): wave=(qg,ktw); stage K DMA, S=K*Q^T, exp, write P-frag.
//   waves 4-7 (PV): e-strip pw*128; V loads, PV MFMA into O[2][8].
// Handoff: Ps double-buffer across the per-iter barrier (QK writes Ps[it&1],
// PV consumes Ps[(it-1)&1]). EXACTLY 130 barriers on each side.
// Full key range -> complete row sums -> in-kernel normalize, direct f32 out.
// ---------------------------------------------------------------------------
__global__ __launch_bounds__(512, 4) void flash_kernel(
    const bf16_t* __restrict__ kp, const bf16_t* __restrict__ qt,
    float* __restrict__ out)
{
    __shared__ alignas(16) bf16_t Ks[2][32 * 512];   // 64 KB, frag-major
    __shared__ alignas(16) bf16_t Ps[2][2 * 512];    //  4 KB, frag-major (32q x 32k)
    __shared__ float Ls[4][16];                      // per-QK-wave row sums
    __shared__ float Lf[32];                         // 1/L per q-row

    const int t    = threadIdx.x;
    const int lane = t & 63;
    const int w    = t >> 6;        // 0..7
    const int l15  = lane & 15;
    const int quad = lane >> 4;

    // XCD remap: 512 blocks; xcd owns one (batch, q-half); 64 blocks/XCD
    const int L      = blockIdx.x;              // 0..511
    const int xcd    = L & 7;
    const int slot   = L >> 3;                  // 0..63
    const int batch  = xcd >> 1;                // 0..3
    const int qtile  = (xcd & 1) * 64 + slot;   // 0..127 (32-row q tiles)

    const int q0 = qtile * 32;
    const bf16_t* kpb = kp + (size_t)batch * SEQ * EMBED;
    const bf16_t* qtb = qt + (size_t)batch * EMBED * SEQ;

    if (w < 4) {
        // ================= producer: QK + softmax-exp =================
        const int qg  = w >> 1;     // 16-q group 0..1
        const int ktw = w & 1;      // 16-key half 0..1

        // stage K-tile 0: 32 frags, 8 per wave, linear DMA
#pragma unroll
        for (int cc = 0; cc < 8; ++cc) {
            const int f = cc * 4 + w;
            async_copy16(&kpb[(size_t)f * 512 + lane * 8], &Ks[0][f * 512]);
        }
        // Q B-frags for q-rows q0+qg*16..+15 (kperm tile = qtile, half = qg)
        bf16x8 bQ[16];
        {
            const size_t qb = (size_t)qtile * 16384 + (size_t)qg * 16 * 512;
#pragma unroll
            for (int kf = 0; kf < 16; ++kf)
                bQ[kf] = *(const bf16x8*)&kpb[qb + kf * 512 + lane * 8];
        }
        float lpart = 0.f;

        for (int it = 0; it < FITERS; ++it) {
            const int cbuf = it & 1;
            const int pbuf = cbuf ^ 1;
            __syncthreads();   // B(it+1): DMA K(it) landed; Ks[pbuf] reads done
            if (it + 1 < FITERS) {
#pragma unroll
                for (int cc = 0; cc < 8; ++cc) {
                    const int f = cc * 4 + w;
                    async_copy16(&kpb[(size_t)(it + 1) * 16384 + f * 512 + lane * 8],
                                 &Ks[pbuf][f * 512]);
                }
            }
            // S^T tile = K[ktw] x Q[qg]^T, 2x8 MFMA chains
            f32x4 a0 = (f32x4){0.f, 0.f, 0.f, 0.f};
            f32x4 a1 = (f32x4){0.f, 0.f, 0.f, 0.f};
#pragma unroll
            for (int kf = 0; kf < 8; ++kf) {
                bf16x8 ak0 = *(const bf16x8*)&Ks[cbuf][(ktw * 16 + kf) * 512 + lane * 8];
                bf16x8 ak1 = *(const bf16x8*)&Ks[cbuf][(ktw * 16 + 8 + kf) * 512 + lane * 8];
                a0 = __builtin_amdgcn_mfma_f32_16x16x32_bf16(ak0, bQ[kf],     a0, 0, 0, 0);
                a1 = __builtin_amdgcn_mfma_f32_16x16x32_bf16(ak1, bQ[8 + kf], a1, 0, 0, 0);
            }
            f32x4 s = a0 + a1;
            // P = exp(s/8): lane has P[key=ktw*16+quad*4+r][q=l15]
            bf16x4 pk;
#pragma unroll
            for (int r = 0; r < 4; ++r) {
                bf16_t pb = (bf16_t)__expf(s[r] * 0.125f);
                lpart += (float)pb;
                pk[r] = pb;
            }
            *(bf16x4*)&Ps[cbuf][qg * 512 + (ktw * 2 + (quad >> 1)) * 128
                                + l15 * 8 + (quad & 1) * 4] = pk;
        }
        // row sums: per q=l15, sum over quad then across ktw via LDS
        {
            float ls = lpart;
            ls += __shfl_xor(ls, 16);
            ls += __shfl_xor(ls, 32);
            if (lane < 16) Ls[w][lane] = ls;
        }
        __syncthreads();   // B129: Ls visible; PV does final PV
        if (t < 32)
            Lf[t] = 1.0f / (Ls[(t >> 4) * 2][t & 15] + Ls[(t >> 4) * 2 + 1][t & 15]);
        __syncthreads();   // B130: Lf visible
    } else {
        // ================= consumer: PV =================
        const int pw = w - 4;       // e-strip pw*128
        f32x4 O[2][8];
#pragma unroll
        for (int m = 0; m < 2; ++m)
#pragma unroll
            for (int n = 0; n < 8; ++n) O[m][n] = (f32x4){0.f, 0.f, 0.f, 0.f};

        for (int it = 0; it < FITERS; ++it) {
            __syncthreads();   // B(it+1): Ps[(it-1)&1] visible
            if (it) {
                const int pbuf = (it & 1) ^ 1;
                const int kv = (it - 1) * BC;
                bf16x8 pa[2];
#pragma unroll
                for (int mt = 0; mt < 2; ++mt)
                    pa[mt] = *(const bf16x8*)&Ps[pbuf][mt * 512 + lane * 8];
#pragma unroll
                for (int nh = 0; nh < 2; ++nh) {
                    bf16x8 bv[4];
#pragma unroll
                    for (int j = 0; j < 4; ++j)
                        bv[j] = *(const bf16x8*)&qtb[(size_t)(pw * 128 + (nh * 4 + j) * 16 + l15) * 4096
                                                     + kv + quad * 8];
                    __builtin_amdgcn_s_setprio(1);
#pragma unroll
                    for (int j = 0; j < 4; ++j)
#pragma unroll
                        for (int mt = 0; mt < 2; ++mt)
                            O[mt][nh * 4 + j] = __builtin_amdgcn_mfma_f32_16x16x32_bf16(
                                pa[mt], bv[j], O[mt][nh * 4 + j], 0, 0, 0);
                    __builtin_amdgcn_s_setprio(0);
                }
            }
        }
        __syncthreads();   // B129: Ps[(FITERS-1)&1] visible
        {   // final PV(FITERS-1)
            const int pbuf = (FITERS - 1) & 1;
            const int kv = (FITERS - 1) * BC;
            bf16x8 pa[2];
#pragma unroll
            for (int mt = 0; mt < 2; ++mt)
                pa[mt] = *(const bf16x8*)&Ps[pbuf][mt * 512 + lane * 8];
#pragma unroll
            for (int nh = 0; nh < 2; ++nh) {
                bf16x8 bv[4];
#pragma unroll
                for (int j = 0; j < 4; ++j)
                    bv[j] = *(const bf16x8*)&qtb[(size_t)(pw * 128 + (nh * 4 + j) * 16 + l15) * 4096
                                                 + kv + quad * 8];
                __builtin_amdgcn_s_setprio(1);
#pragma unroll
                for (int j = 0; j < 4; ++j)
#pragma unroll
                    for (int mt = 0; mt < 2; ++mt)
                        O[mt][nh * 4 + j] = __builtin_amdgcn_mfma_f32_16x16x32_bf16(
                            pa[mt], bv[j], O[mt][nh * 4 + j], 0, 0, 0);
                __builtin_amdgcn_s_setprio(0);
            }
        }
        __syncthreads();   // B130: Lf visible
        // normalized O -> out; D: row(q)=quad*4+r, col(e)=l15
#pragma unroll
        for (int mt = 0; mt < 2; ++mt)
#pragma unroll
            for (int r = 0; r < 4; ++r) {
                const int qloc = mt * 16 + quad * 4 + r;
                const float inv = Lf[qloc];
                const size_t row = (size_t)batch * SEQ + q0 + qloc;
#pragma unroll
                for (int n = 0; n < 8; ++n)
                    __builtin_nontemporal_store(O[mt][n][r] * inv,
                        &out[row * 512 + pw * 128 + n * 16 + l15]);
            }
    }
}

extern "C" void kernel_launch(void* const* d_in, const int* in_sizes, int n_in,
                              void* d_out, int out_size, void* d_ws, size_t ws_size,
                              hipStream_t stream) {
    const float* x     = (const float*)d_in[0];
    const float* theta = (const float*)d_in[1];
    const float* W     = (const float*)d_in[2];
    const float* bias  = (const float*)d_in[3];
    float* out    = (float*)d_out;
    bf16_t* kperm = (bf16_t*)d_ws;                      // [4][128 tiles][32 frags][512] bf16
    bf16_t* qt    = kperm + (size_t)MTOT * EMBED;       // [4][512][4096] bf16
    bf16_t* abuf  = qt + (size_t)MTOT * EMBED;          // [16384][512] bf16

    cvt_w_kernel<<<dim3(EMBED * EMBED / 4 / 256), dim3(256), 0, stream>>>(W);

    cvt_a_kernel<<<dim3(MTOT * EMBED / 8 / 256), dim3(256), 0, stream>>>(x, theta, abuf);

    gemm_q_kernel<<<dim3((MTOT / 128) * 4), dim3(256), 0, stream>>>(abuf, bias, kperm, qt);

    flash_kernel<<<dim3(SEQ / 32 * BATCH), dim3(512), 0, stream>>>(kperm, qt, out);
}